// Round 12
// baseline (124.095 us; speedup 1.0000x reference)
//
#include <hip/hip_runtime.h>
#include <math.h>

#define B_ 256
#define S_ 50
#define K_ 20
#define D_ 128
#define G3 384          // 3*D
#define M_  (B_ * S_)   // 12800 (b,s) rows

// ---------------------------------------------------------------------------
// Kernel P: basket pooling. 256 thr/block = two (b,s) rows; 6400 blocks.
// ---------------------------------------------------------------------------
__global__ __launch_bounds__(256) void pool_kernel(
    const int* __restrict__ items, const int* __restrict__ basket_len,
    const int* __restrict__ lengths, const float* __restrict__ encode,
    float* __restrict__ pooled)
{
    const int tid  = threadIdx.x;
    const int pair = tid >> 7;
    const int d    = tid & 127;
    const int m    = blockIdx.x * 2 + pair;   // (b,s) row id
    const int b    = m / S_;
    const int s    = m % S_;
    const int len  = lengths[b];

    float p = 0.f;
    if (s < len) {
        const int  blen = basket_len[m];
        const int* it   = items + m * K_;
        for (int k = 0; k < blen; ++k)
            p += encode[(long)it[k] * D_ + d];
        p /= (float)blen;
    }
    pooled[m * D_ + d] = p;
}

// ---------------------------------------------------------------------------
// Kernel G: gx = pooled @ w_ih^T + b_ih. M=12800, N=384, K=128.
// ---------------------------------------------------------------------------
__global__ __launch_bounds__(256) void gx_gemm_kernel(
    const float* __restrict__ pooled, const float* __restrict__ w_ih,
    const float* __restrict__ b_ih, float* __restrict__ gx)
{
    __shared__ float As[32][64];    // [k][m]
    __shared__ float Bs[32][128];   // [k][n]

    const int tid = threadIdx.x;
    const int bm  = blockIdx.x % 200;
    const int bn  = blockIdx.x / 200;
    const int m0  = bm * 64;
    const int n0  = bn * 128;
    const int tx  = tid & 15;               // -> N
    const int ty  = tid >> 4;               // -> M

    float acc[4][8] = {};

    for (int kt = 0; kt < 128; kt += 32) {
        #pragma unroll
        for (int i = 0; i < 2; ++i) {
            int idx = tid + 256 * i;
            int r = idx >> 3, c = idx & 7;
            float4 v = *reinterpret_cast<const float4*>(
                pooled + (m0 + r) * 128 + kt + c * 4);
            As[c*4+0][r] = v.x; As[c*4+1][r] = v.y;
            As[c*4+2][r] = v.z; As[c*4+3][r] = v.w;
        }
        #pragma unroll
        for (int i = 0; i < 4; ++i) {
            int idx = tid + 256 * i;
            int r = idx >> 3, c = idx & 7;
            float4 v = *reinterpret_cast<const float4*>(
                w_ih + (n0 + r) * 128 + kt + c * 4);
            Bs[c*4+0][r] = v.x; Bs[c*4+1][r] = v.y;
            Bs[c*4+2][r] = v.z; Bs[c*4+3][r] = v.w;
        }
        __syncthreads();

        #pragma unroll
        for (int k = 0; k < 32; ++k) {
            float4 a  = *reinterpret_cast<const float4*>(&As[k][ty * 4]);
            float4 b0 = *reinterpret_cast<const float4*>(&Bs[k][tx * 8]);
            float4 b1 = *reinterpret_cast<const float4*>(&Bs[k][tx * 8 + 4]);
            float av[4] = {a.x, a.y, a.z, a.w};
            float bv[8] = {b0.x, b0.y, b0.z, b0.w, b1.x, b1.y, b1.z, b1.w};
            #pragma unroll
            for (int mi = 0; mi < 4; ++mi)
                #pragma unroll
                for (int ni = 0; ni < 8; ++ni)
                    acc[mi][ni] = fmaf(av[mi], bv[ni], acc[mi][ni]);
        }
        __syncthreads();
    }

    float bias[8];
    #pragma unroll
    for (int ni = 0; ni < 8; ++ni) bias[ni] = b_ih[n0 + tx * 8 + ni];
    #pragma unroll
    for (int mi = 0; mi < 4; ++mi) {
        const int row = m0 + ty * 4 + mi;
        float4 o0, o1;
        o0.x = acc[mi][0] + bias[0]; o0.y = acc[mi][1] + bias[1];
        o0.z = acc[mi][2] + bias[2]; o0.w = acc[mi][3] + bias[3];
        o1.x = acc[mi][4] + bias[4]; o1.y = acc[mi][5] + bias[5];
        o1.z = acc[mi][6] + bias[6]; o1.w = acc[mi][7] + bias[7];
        float* dst = gx + (long)row * G3 + n0 + tx * 8;
        *reinterpret_cast<float4*>(dst)     = o0;
        *reinterpret_cast<float4*>(dst + 4) = o1;
    }
}

// ---------------------------------------------------------------------------
// Kernel B v4: sequential GRU. 256 blocks, 768 threads, 2 threads per output
// row; 64 weights per thread in 64 NAMED SCALAR floats, asm-pinned per scalar
// (R10: "+v" on float4 rejected — tied indirect register inputs; scalars are
// the supported case). No arrays -> nothing demotable to scratch (rule #20).
// ---------------------------------------------------------------------------
#define LOADW(i) \
    float4 t##i = wrow[i]; \
    float wa##i = t##i.x, wb##i = t##i.y, wc##i = t##i.z, wd##i = t##i.w; \
    asm volatile("" : "+v"(wa##i), "+v"(wb##i), "+v"(wc##i), "+v"(wd##i));

#define DOTW(i) { \
    float4 hv = h4[hbase + i]; \
    acc = fmaf(hv.x, wa##i, acc); acc = fmaf(hv.y, wb##i, acc); \
    acc = fmaf(hv.z, wc##i, acc); acc = fmaf(hv.w, wd##i, acc); }

__global__ __launch_bounds__(768, 3) void gru_kernel(
    const int* __restrict__ lengths, const float* __restrict__ w_hh,
    const float* __restrict__ b_hh, const float* __restrict__ h0,
    const float* __restrict__ gx, float* __restrict__ out)
{
    const int b    = blockIdx.x;
    const int len  = lengths[b];
    const int tid  = threadIdx.x;
    const int j    = tid >> 1;     // output row 0..383
    const int half = tid & 1;      // which K-half this thread owns

    // 64 weights in 64 named scalar registers — one-time load from L2
    const float4* wrow = reinterpret_cast<const float4*>(w_hh + j * D_ + half * 64);
    LOADW(0)  LOADW(1)  LOADW(2)  LOADW(3)
    LOADW(4)  LOADW(5)  LOADW(6)  LOADW(7)
    LOADW(8)  LOADW(9)  LOADW(10) LOADW(11)
    LOADW(12) LOADW(13) LOADW(14) LOADW(15)

    const float bias = half ? 0.f : b_hh[j];   // bias counted once per pair

    __shared__ float4 h4[32];     // hidden state, 128 f32
    __shared__ float  gh[G3];
    if (tid < 128) ((float*)h4)[tid] = h0[b * D_ + tid];
    __syncthreads();

    float* ys = out;                          // (B,S,D)
    float* hu = out + (long)B_ * S_ * D_;     // (B,D)

    const int hbase = half * 16;              // float4 offset into h

    for (int s = 0; s < len; ++s) {
        // gx loads issued before the dot (independent of h -> overlap)
        float gxr = 0.f, gxz = 0.f, gxn = 0.f;
        if (tid < 128) {
            const float* gxp = gx + ((long)b * S_ + s) * G3;
            gxr = gxp[tid]; gxz = gxp[128 + tid]; gxn = gxp[256 + tid];
        }
        // partial dot over this thread's 64-element K-range, fully static
        float acc = bias;
        DOTW(0)  DOTW(1)  DOTW(2)  DOTW(3)
        DOTW(4)  DOTW(5)  DOTW(6)  DOTW(7)
        DOTW(8)  DOTW(9)  DOTW(10) DOTW(11)
        DOTW(12) DOTW(13) DOTW(14) DOTW(15)
        // pair-combine: lanes 2j and 2j+1 adjacent in the wave
        acc += __shfl_xor(acc, 1);
        gh[j] = acc;                 // both lanes write the same value
        __syncthreads();
        if (tid < 128) {
            float ghr = gh[tid], ghz = gh[128 + tid], ghn = gh[256 + tid];
            float r = 1.f / (1.f + expf(-(gxr + ghr)));
            float z = 1.f / (1.f + expf(-(gxz + ghz)));
            float n = tanhf(gxn + r * ghn);
            float hprev = ((float*)h4)[tid];
            float hn = (1.f - z) * n + z * hprev;
            ys[((long)b * S_ + s) * D_ + tid] = hn;
            ((float*)h4)[tid] = hn;
        }
        __syncthreads();
    }
    if (tid < 128) {
        hu[b * D_ + tid] = ((float*)h4)[tid];
        for (int s = len; s < S_; ++s)
            ys[((long)b * S_ + s) * D_ + tid] = 0.f;
    }
}

extern "C" void kernel_launch(void* const* d_in, const int* in_sizes, int n_in,
                              void* d_out, int out_size, void* d_ws, size_t ws_size,
                              hipStream_t stream) {
    const int*   items      = (const int*)d_in[0];
    const int*   basket_len = (const int*)d_in[1];
    const int*   lengths    = (const int*)d_in[2];
    const float* encode     = (const float*)d_in[3];
    const float* w_ih       = (const float*)d_in[4];
    const float* w_hh       = (const float*)d_in[5];
    const float* b_ih       = (const float*)d_in[6];
    const float* b_hh       = (const float*)d_in[7];
    const float* h0         = (const float*)d_in[8];
    float* out = (float*)d_out;

    float* gx     = (float*)d_ws;                       // 12800*384 f32 = 19.66 MB
    float* pooled = gx + (long)M_ * G3;                 // 12800*128 f32 =  6.55 MB

    pool_kernel<<<M_ / 2, 256, 0, stream>>>(
        items, basket_len, lengths, encode, pooled);
    gx_gemm_kernel<<<600, 256, 0, stream>>>(
        pooled, w_ih, b_ih, gx);
    gru_kernel<<<B_, 768, 0, stream>>>(
        lengths, w_hh, b_hh, h0, gx, out);
}